// Round 15
// baseline (28.783 us; speedup 1.0000x reference)
//
#include <hip/hip_runtime.h>
#include <hip/hip_bf16.h>

#define NB 4
#define NH 16
#define SEQ 2048
#define EMB 512
#define DH 32
#define CHUNKQ 64
#define WIN 256

typedef __attribute__((ext_vector_type(8))) short short8;
typedef __attribute__((ext_vector_type(4))) float f32x4;

// packed f32x2 -> bf16x2 (RNE); HW-validated rounds 3/6/8
__device__ __forceinline__ unsigned cvt_pk_bf16(float lo, float hi) {
    unsigned r;
    asm("v_cvt_pk_bf16_f32 %0, %1, %2" : "=v"(r) : "v"(lo), "v"(hi));
    return r;
}

// === r8 (green, 26.4us) + ONE delta: shfl-butterfly P transit (no Pbuf) ===
// Why: DS ops complete in-order through ONE lgkmcnt per wave, so r8's
// per-iteration ds_write x2 -> wait -> ds_read -> wait round-trip is two
// SEQUENTIAL LDS latencies that cannot pipeline (this also explains r12's
// neutral 2-stream probe: both streams queued in the same in-order DS pipe).
// The transit is a FIXED 64-lane permutation: dest (q=l16, kg) A-frag words
// come from srcA = l16+32*(kg&1) and srcB = srcA+16, half-selected by kg<2.
// 8 independent __shfl (ds_bpermute) + 4 selects = ONE parallel LDS latency.
// Vt/B-side and all other mechanics byte-identical to r8; pa assembled with
// the union idiom already green for qb (r6/r8).
// Verified mapping on concrete lanes: (l16=5,kg=1)w0 <- lane37.lo;
// (5,2)w0 <- lane5.hi; (2,0)w2 <- lane18.lo; (5,3)w3 <- lane53.hi.
//
// LDS: Ks [320][40] (25600) + Vt [32][328] (20992) = 46592 B -> 3 blocks/CU.

__global__ __launch_bounds__(256, 3)
void attn_chunk_kernel(const float* __restrict__ q, const float* __restrict__ k,
                       const float* __restrict__ v, float* __restrict__ out)
{
    constexpr int KSTR = 40;    // Ks row stride (bf16)
    constexpr int VSTR = 328;   // Vt row stride (bf16)
    __shared__ __align__(16) ushort Ks[320 * KSTR];
    __shared__ __align__(16) ushort Vt[32 * VSTR];

    // XCD-aware swizzle: 2048 blocks, 8 XCDs -> contiguous 256-block chunk/XCD
    const unsigned bid = (blockIdx.x & 7) * 256 + (blockIdx.x >> 3);
    const int cid = bid & 31;          // chunk id
    const int h   = (bid >> 5) & 15;   // head
    const int b   = bid >> 9;          // batch
    const int q0  = cid * CHUNKQ;
    const int hi  = q0 + CHUNKQ;
    const int kstart = (hi - 320 > 0) ? (hi - 320) : 0;
    const int KT  = hi - kstart;       // 64..320, multiple of 64

    const int tid = threadIdx.x;
    const int e4  = (tid & 7) * 4;     // K-staging dim 0,4,..,28
    const int r0  = tid >> 3;          // K-staging key row 0..31
    const int d2  = (tid & 15) * 2;    // V-staging dim pair 0,2,..,30
    const int kp  = tid >> 4;          // V-staging key-pair 0..15

    // ---- staging loads: ALL issued first, unconditional (always in-bounds:
    //      kstart + row <= hi-1 <= 2047; extra cols written but never read) ----
    float4 fk[10];
    float2 va[10], vb[10];
    #pragma unroll
    for (int it = 0; it < 10; ++it) {
        const size_t kbase = (size_t)(b * SEQ + kstart + r0 + it * 32) * EMB + h * DH + e4;
        fk[it] = *(const float4*)(k + kbase);
        const size_t vbase = (size_t)(b * SEQ + kstart + 32 * it + 2 * kp) * EMB + h * DH + d2;
        va[it] = *(const float2*)(v + vbase);          // key 32it+2kp, dims d2,d2+1
        vb[it] = *(const float2*)(v + vbase + EMB);    // key 32it+2kp+1
    }

    const int w   = tid >> 6;          // wave 0..3 owns queries [16w, 16w+16)
    const int l   = tid & 63;
    const int l16 = l & 15;
    const int kg  = l >> 4;            // 0..3
    const int k0  = kg * 8;            // dim slice for frags

    // ---- Q B-frag direct from global (overlaps the staging-load latency) ----
    const float* qrow = q + ((size_t)(b * SEQ + q0 + 16 * w + l16) * EMB + h * DH + k0);
    const float4 qa = *(const float4*)qrow;
    const float4 qc = *(const float4*)(qrow + 4);
    union { short8 s; unsigned u[4]; } qb;
    qb.u[0] = cvt_pk_bf16(qa.x, qa.y);
    qb.u[1] = cvt_pk_bf16(qa.z, qa.w);
    qb.u[2] = cvt_pk_bf16(qc.x, qc.y);
    qb.u[3] = cvt_pk_bf16(qc.z, qc.w);

    // ---- staging converts + LDS writes (unconditional) ----
    #pragma unroll
    for (int it = 0; it < 10; ++it) {
        uint2 kw;
        kw.x = cvt_pk_bf16(fk[it].x, fk[it].y);
        kw.y = cvt_pk_bf16(fk[it].z, fk[it].w);
        *(uint2*)(Ks + (r0 + it * 32) * KSTR + e4) = kw;   // 8B aligned
        *(unsigned*)(Vt + (d2 + 0) * VSTR + 32 * it + 2 * kp) = cvt_pk_bf16(va[it].x, vb[it].x);
        *(unsigned*)(Vt + (d2 + 1) * VSTR + 32 * it + 2 * kp) = cvt_pk_bf16(va[it].y, vb[it].y);
    }
    __syncthreads();   // the only barrier

    const float scale = 0.17677669529663687f;  // 1/sqrt(32)
    const int   iq    = q0 + 16 * w + l16;     // this lane's query (key-major domain)
    const int   lowk  = iq - (WIN - 1);        // allowed keys: [lowk, hi)

    // shfl-butterfly source lanes (fixed per lane)
    const int srcA = l16 + ((kg & 1) << 5);    // kg'=0,2 -> kg0; kg'=1,3 -> kg2
    const int srcB = srcA + 16;                // kg1 / kg3
    const bool lohalf = (kg < 2);

    const f32x4 zero = {0.f, 0.f, 0.f, 0.f};
    f32x4 o0 = zero, o1 = zero;
    float srow = 0.f;

    #pragma unroll
    for (int t = 0; t < 10; ++t) {
        if (t * 32 < KT) {
            // QK^T (swapped): A = K rows, B = Q. D[key=4kg+r / 16+4kg+r][q=l16]
            const short8 ka = *(const short8*)(Ks + (32 * t + l16) * KSTR + k0);
            const short8 kb = *(const short8*)(Ks + (32 * t + 16 + l16) * KSTR + k0);
            f32x4 s_lo = __builtin_amdgcn_mfma_f32_16x16x32_bf16(ka, qb.s, zero, 0, 0, 0);
            f32x4 s_hi = __builtin_amdgcn_mfma_f32_16x16x32_bf16(kb, qb.s, zero, 0, 0, 0);

            // mask + exp (no max-sub: scores bounded, fp32-safe); sum in-lane
            const int kk = kstart + 32 * t + 4 * kg;
            float p[8];
            #pragma unroll
            for (int r = 0; r < 4; ++r) {
                p[r]     = (kk + r      >= lowk) ? __expf(s_lo[r] * scale) : 0.f;
                p[r + 4] = (kk + r + 16 >= lowk) ? __expf(s_hi[r] * scale) : 0.f;
            }
            srow += ((p[0] + p[1]) + (p[2] + p[3])) + ((p[4] + p[5]) + (p[6] + p[7]));

            // pack own p's, then shfl-butterfly into true A-frag layout:
            // pa word j at (l16,kg) = P[q=l16][key 8kg+2j..+1]
            const unsigned lo0 = cvt_pk_bf16(p[0], p[1]);   // own keys 4kg+0,1
            const unsigned lo1 = cvt_pk_bf16(p[2], p[3]);   // own keys 4kg+2,3
            const unsigned hi0 = cvt_pk_bf16(p[4], p[5]);   // own keys 16+4kg+0,1
            const unsigned hi1 = cvt_pk_bf16(p[6], p[7]);   // own keys 16+4kg+2,3
            const unsigned aL0 = (unsigned)__shfl((int)lo0, srcA);
            const unsigned aL1 = (unsigned)__shfl((int)lo1, srcA);
            const unsigned aH0 = (unsigned)__shfl((int)hi0, srcA);
            const unsigned aH1 = (unsigned)__shfl((int)hi1, srcA);
            const unsigned bL0 = (unsigned)__shfl((int)lo0, srcB);
            const unsigned bL1 = (unsigned)__shfl((int)lo1, srcB);
            const unsigned bH0 = (unsigned)__shfl((int)hi0, srcB);
            const unsigned bH1 = (unsigned)__shfl((int)hi1, srcB);
            union { short8 s; unsigned u[4]; } pa;
            pa.u[0] = lohalf ? aL0 : aH0;
            pa.u[1] = lohalf ? aL1 : aH1;
            pa.u[2] = lohalf ? bL0 : bH0;
            pa.u[3] = lohalf ? bL1 : bH1;

            // PV: B = Vt rows (dims), accumulate (identical to r8)
            const short8 bv0 = *(const short8*)(Vt + l16 * VSTR + 32 * t + k0);
            const short8 bv1 = *(const short8*)(Vt + (16 + l16) * VSTR + 32 * t + k0);
            o0 = __builtin_amdgcn_mfma_f32_16x16x32_bf16(pa.s, bv0, o0, 0, 0, 0);
            o1 = __builtin_amdgcn_mfma_f32_16x16x32_bf16(pa.s, bv1, o1, 0, 0, 0);
        }
    }

    // ---- epilogue: reduce row-sum (keys partitioned over kg/halves), write ----
    srow += __shfl_xor(srow, 16);
    srow += __shfl_xor(srow, 32);   // srow(q=l16) valid in all kg groups
    #pragma unroll
    for (int r = 0; r < 4; ++r) {
        const float sq  = __shfl(srow, 4 * kg + r);     // srow for query 4kg+r
        const float inv = 1.0f / sq;
        float* dst = out + (size_t)(b * SEQ + q0 + 16 * w + 4 * kg + r) * EMB + h * DH;
        dst[l16]      = o0[r] * inv;
        dst[16 + l16] = o1[r] * inv;
    }
}

extern "C" void kernel_launch(void* const* d_in, const int* in_sizes, int n_in,
                              void* d_out, int out_size, void* d_ws, size_t ws_size,
                              hipStream_t stream) {
    const float* q = (const float*)d_in[0];
    const float* k = (const float*)d_in[1];
    const float* v = (const float*)d_in[2];
    float* out = (float*)d_out;
    const int grid = NB * NH * (SEQ / CHUNKQ);   // 2048 blocks
    attn_chunk_kernel<<<grid, 256, 0, stream>>>(q, k, v, out);
}